// Round 1
// baseline (363.894 us; speedup 1.0000x reference)
//
#include <hip/hip_runtime.h>
#include <hip/hip_bf16.h>

// GTO_Atten pipeline, MI355X (gfx950).
// Stages: prep -> kv1 GEMM -> attn1(split)+combine+kv2 -> q3 GEMM -> attn2 -> proj GEMM.
// All matmuls on v_mfma_f32_16x16x32_bf16 (fp32 accum). Workspace ~119 MB.

#define NB 4
#define NSEQ 8192
#define CD 512
#define NH 8
#define TD 64
#define NTOK 256
#define NSPLIT 8
#define NKEYS (NSEQ / NSPLIT)

typedef unsigned short u16;
typedef __bf16 bf16x8 __attribute__((ext_vector_type(8)));
typedef float f32x4 __attribute__((ext_vector_type(4)));

__device__ __forceinline__ u16 f2bf(float f){
  __hip_bfloat16 h = __float2bfloat16(f);
  u16 u; __builtin_memcpy(&u, &h, 2); return u;
}
__device__ __forceinline__ bf16x8 ld8(const u16* p){
  bf16x8 r; __builtin_memcpy(&r, p, 16); return r;
}
__device__ __forceinline__ f32x4 mfma16(bf16x8 a, bf16x8 b, f32x4 c){
  return __builtin_amdgcn_mfma_f32_16x16x32_bf16(a, b, c, 0, 0, 0);
}

// ---------------- K0: prep (weights -> bf16 transposed [n][k]; Q,q3_w pre-scaled) ----
__global__ void k_prep(const float* __restrict__ kv1_w, const float* __restrict__ q3_w,
                       const float* __restrict__ proj_w, const float* __restrict__ Q,
                       u16* __restrict__ kv1_wt, u16* __restrict__ q3_wt,
                       u16* __restrict__ proj_wt, u16* __restrict__ Qb){
  int i = blockIdx.x * 256 + threadIdx.x;
  if (i < CD*CD){
    int k = i >> 9, n = i & 511;
    kv1_wt [n*CD + k] = f2bf(kv1_w[i]);
    q3_wt  [n*CD + k] = f2bf(q3_w[i] * 0.125f);   // fold 1/sqrt(td)
    proj_wt[n*CD + k] = f2bf(proj_w[i]);
  }
  if (i < NH*NTOK*TD) Qb[i] = f2bf(Q[i] * 0.125f); // fold 1/sqrt(td)
}

// ---------------- GEMM: C[M][512] = A[M][512] @ B + bias; Bt is [n][k] bf16 ---------
template<int A_F32, int OUT_F32>
__global__ __launch_bounds__(256, 2)
void k_gemm512(const void* __restrict__ Ap, const u16* __restrict__ Bt,
               const float* __restrict__ bias, float bscale, void* __restrict__ outp){
  __shared__ __attribute__((aligned(16))) u16 As[128][72];
  __shared__ __attribute__((aligned(16))) u16 Bs[128][72];
  const int tid = threadIdx.x;
  const int lane = tid & 63, wave = tid >> 6;
  const int l15 = lane & 15, lg = lane >> 4;
  const int wm = (wave >> 1) * 64, wn = (wave & 1) * 64;
  const int bm = blockIdx.x, bn = blockIdx.y;
  f32x4 acc[4][4] = {};

#pragma unroll 1
  for (int k0 = 0; k0 < CD; k0 += 64){
    __syncthreads();
    if constexpr (A_F32){
      const float* A = (const float*)Ap;
      int r0 = tid >> 4, c4 = (tid & 15) << 2;
#pragma unroll
      for (int rr = 0; rr < 128; rr += 16){
        const float* src = A + (size_t)(bm*128 + r0 + rr) * CD + k0 + c4;
        float4 v = *(const float4*)src;
        u16 w[4] = { f2bf(v.x), f2bf(v.y), f2bf(v.z), f2bf(v.w) };
        __builtin_memcpy(&As[r0 + rr][c4], w, 8);
      }
    } else {
      const u16* A = (const u16*)Ap;
      int r0 = tid >> 3, c8 = (tid & 7) << 3;
#pragma unroll
      for (int rr = 0; rr < 128; rr += 32){
        const u16* src = A + (size_t)(bm*128 + r0 + rr) * CD + k0 + c8;
        int4 v = *(const int4*)src;
        __builtin_memcpy(&As[r0 + rr][c8], &v, 16);
      }
    }
    {
      int r0 = tid >> 3, c8 = (tid & 7) << 3;
#pragma unroll
      for (int rr = 0; rr < 128; rr += 32){
        const u16* src = Bt + (size_t)(bn*128 + r0 + rr) * CD + k0 + c8;
        int4 v = *(const int4*)src;
        __builtin_memcpy(&Bs[r0 + rr][c8], &v, 16);
      }
    }
    __syncthreads();
#pragma unroll
    for (int ks = 0; ks < 2; ks++){
      bf16x8 af[4], bfr[4];
#pragma unroll
      for (int mf = 0; mf < 4; mf++) af[mf]  = ld8(&As[wm + mf*16 + l15][ks*32 + lg*8]);
#pragma unroll
      for (int nf = 0; nf < 4; nf++) bfr[nf] = ld8(&Bs[wn + nf*16 + l15][ks*32 + lg*8]);
#pragma unroll
      for (int mf = 0; mf < 4; mf++)
#pragma unroll
        for (int nf = 0; nf < 4; nf++)
          acc[mf][nf] = mfma16(af[mf], bfr[nf], acc[mf][nf]);
    }
  }
#pragma unroll
  for (int nf = 0; nf < 4; nf++){
    int col = bn*128 + wn + nf*16 + l15;
    float bv = bias[col] * bscale;
#pragma unroll
    for (int mf = 0; mf < 4; mf++){
      int row = bm*128 + wm + mf*16 + lg*4;
#pragma unroll
      for (int q = 0; q < 4; q++){
        float v = acc[mf][nf][q] + bv;
        if constexpr (OUT_F32) ((float*)outp)[(size_t)(row + q)*CD + col] = v;
        else                   ((u16*)outp)[(size_t)(row + q)*CD + col] = f2bf(v);
      }
    }
  }
}

// ---------------- K2: attn1 partial flash (split over n) ---------------------------
__global__ __launch_bounds__(256, 2)
void k_attn1(const u16* __restrict__ kv1, const u16* __restrict__ Qb,
             float* __restrict__ o_part, float* __restrict__ ml_part){
  __shared__ __attribute__((aligned(16))) u16 kvs[64][72];   // [n][td]
  __shared__ __attribute__((aligned(16))) u16 kvts[64][72];  // [td][n]
  __shared__ __attribute__((aligned(16))) u16 pws[4][64][72]; // per-wave P bf16 [m][n]
  const int tid = threadIdx.x, lane = tid & 63, wave = tid >> 6;
  const int blk = blockIdx.x;                // bh*NSPLIT + s
  const int bh = blk / NSPLIT, s = blk % NSPLIT;
  const int b = bh >> 3, h = bh & 7;
  const int l15 = lane & 15, lg = lane >> 4;
  const int m0 = wave * 64;

  bf16x8 qf[4][2];
#pragma unroll
  for (int mf = 0; mf < 4; mf++)
#pragma unroll
    for (int ks = 0; ks < 2; ks++)
      qf[mf][ks] = ld8(Qb + (size_t)(h*NTOK + m0 + mf*16 + l15)*TD + ks*32 + lg*8);

  float mst[4][4], lst[4][4];
  f32x4 oac[4][4] = {};
#pragma unroll
  for (int mf = 0; mf < 4; mf++)
#pragma unroll
    for (int q = 0; q < 4; q++){ mst[mf][q] = -1e30f; lst[mf][q] = 0.f; }

  const int nbase = s * NKEYS;
#pragma unroll 1
  for (int c = 0; c < NKEYS/64; c++){
    const int nc = nbase + c*64;
    __syncthreads();
    {
      int r = tid >> 2, seg = (tid & 3) * 16;
      const u16* src = kv1 + (size_t)(b*NSEQ + nc + r)*CD + h*TD + seg;
      int4 v0 = *(const int4*)src;
      int4 v1 = *(const int4*)(src + 8);
      __builtin_memcpy(&kvs[r][seg],     &v0, 16);
      __builtin_memcpy(&kvs[r][seg + 8], &v1, 16);
      u16 tmp[16];
      __builtin_memcpy(tmp,     &v0, 16);
      __builtin_memcpy(tmp + 8, &v1, 16);
#pragma unroll
      for (int j = 0; j < 16; j++) kvts[seg + j][r] = tmp[j];
    }
    __syncthreads();
    // logits (pre-scaled via Qb)
    f32x4 d[4][4] = {};
#pragma unroll
    for (int nf = 0; nf < 4; nf++)
#pragma unroll
      for (int ks = 0; ks < 2; ks++){
        bf16x8 kf = ld8(&kvs[nf*16 + l15][ks*32 + lg*8]);
#pragma unroll
        for (int mf = 0; mf < 4; mf++) d[mf][nf] = mfma16(qf[mf][ks], kf, d[mf][nf]);
      }
    // online softmax; rows live in-lane at (l>>4)*4+q
#pragma unroll
    for (int mf = 0; mf < 4; mf++)
#pragma unroll
      for (int q = 0; q < 4; q++){
        float cm = fmaxf(fmaxf(d[mf][0][q], d[mf][1][q]), fmaxf(d[mf][2][q], d[mf][3][q]));
#pragma unroll
        for (int off = 1; off < 16; off <<= 1) cm = fmaxf(cm, __shfl_xor(cm, off, 64));
        float mnew = fmaxf(mst[mf][q], cm);
        float corr = __expf(mst[mf][q] - mnew);
        float rs = 0.f;
#pragma unroll
        for (int nf = 0; nf < 4; nf++){
          float e = __expf(d[mf][nf][q] - mnew);
          d[mf][nf][q] = e; rs += e;
        }
#pragma unroll
        for (int off = 1; off < 16; off <<= 1) rs += __shfl_xor(rs, off, 64);
        lst[mf][q] = lst[mf][q]*corr + rs;
        mst[mf][q] = mnew;
#pragma unroll
        for (int tf = 0; tf < 4; tf++) oac[mf][tf][q] *= corr;
        int ml = mf*16 + lg*4 + q;
#pragma unroll
        for (int nf = 0; nf < 4; nf++) pws[wave][ml][nf*16 + l15] = f2bf(d[mf][nf][q]);
      }
    // PV
#pragma unroll
    for (int ks = 0; ks < 2; ks++){
      bf16x8 a[4];
#pragma unroll
      for (int mf = 0; mf < 4; mf++) a[mf] = ld8(&pws[wave][mf*16 + l15][ks*32 + lg*8]);
#pragma unroll
      for (int tf = 0; tf < 4; tf++){
        bf16x8 vf = ld8(&kvts[tf*16 + l15][ks*32 + lg*8]);
#pragma unroll
        for (int mf = 0; mf < 4; mf++) oac[mf][tf] = mfma16(a[mf], vf, oac[mf][tf]);
      }
    }
  }
  // write partials
#pragma unroll
  for (int mf = 0; mf < 4; mf++)
#pragma unroll
    for (int q = 0; q < 4; q++){
      int m = m0 + mf*16 + lg*4 + q;
#pragma unroll
      for (int tf = 0; tf < 4; tf++)
        o_part[(size_t)(blk*NTOK + m)*TD + tf*16 + l15] = oac[mf][tf][q];
      if (l15 == 0){
        ml_part[(size_t)(blk*2)*NTOK + m]     = mst[mf][q];
        ml_part[(size_t)(blk*2 + 1)*NTOK + m] = lst[mf][q];
      }
    }
}

// ---------------- K3: combine partials + kv2 GEMM (tiny) ---------------------------
__global__ __launch_bounds__(256, 1)
void k_comb(const float* __restrict__ o_part, const float* __restrict__ ml_part,
            const float* __restrict__ qkv2_w, u16* __restrict__ kb, u16* __restrict__ vtb){
  __shared__ float w2[TD][2*TD];
  const int bh = blockIdx.x, m = threadIdx.x;
  for (int i = threadIdx.x; i < TD*2*TD; i += 256) w2[i >> 7][i & 127] = qkv2_w[i];

  float M = -1e30f;
#pragma unroll
  for (int s = 0; s < NSPLIT; s++)
    M = fmaxf(M, ml_part[(size_t)((bh*NSPLIT + s)*2)*NTOK + m]);
  float denom = 0.f, o[TD];
#pragma unroll
  for (int t = 0; t < TD; t++) o[t] = 0.f;
#pragma unroll 1
  for (int s = 0; s < NSPLIT; s++){
    int blk = bh*NSPLIT + s;
    float w = __expf(ml_part[(size_t)(blk*2)*NTOK + m] - M);
    denom += ml_part[(size_t)(blk*2 + 1)*NTOK + m] * w;
    const float4* op = (const float4*)(o_part + (size_t)(blk*NTOK + m)*TD);
#pragma unroll
    for (int t4 = 0; t4 < TD/4; t4++){
      float4 v = op[t4];
      o[t4*4+0] += w*v.x; o[t4*4+1] += w*v.y; o[t4*4+2] += w*v.z; o[t4*4+3] += w*v.w;
    }
  }
  float inv = 1.f / denom;
#pragma unroll
  for (int t = 0; t < TD; t++) o[t] *= inv;   // proj_token row
  __syncthreads();
#pragma unroll 1
  for (int j = 0; j < 2*TD; j++){
    float acc = 0.f;
#pragma unroll
    for (int t = 0; t < TD; t++) acc += o[t] * w2[t][j];
    if (j < TD) kb[(size_t)(bh*NTOK + m)*TD + j] = f2bf(acc);
    else        vtb[(size_t)(bh*TD + (j - TD))*NTOK + m] = f2bf(acc);
  }
}

// ---------------- K5: attn2 (softmax over m=256, fully local) ----------------------
__global__ __launch_bounds__(256, 2)
void k_attn2(const u16* __restrict__ q3, const u16* __restrict__ kb,
             const u16* __restrict__ vtb, u16* __restrict__ Wout){
  __shared__ __attribute__((aligned(16))) u16 pws[4][64][72];
  const int tid = threadIdx.x, lane = tid & 63, wave = tid >> 6;
  const int blk = blockIdx.x;           // bh*32 + nt
  const int bh = blk >> 5, nt = blk & 31;
  const int b = bh >> 3, h = bh & 7;
  const int l15 = lane & 15, lg = lane >> 4;
  const int n0 = nt * 256 + wave * 64;

  bf16x8 qf[4][2];
#pragma unroll
  for (int nf = 0; nf < 4; nf++)
#pragma unroll
    for (int ks = 0; ks < 2; ks++)
      qf[nf][ks] = ld8(q3 + (size_t)(b*NSEQ + n0 + nf*16 + l15)*CD + h*TD + ks*32 + lg*8);

  float mst[4][4], lst[4][4];
  f32x4 oac[4][4] = {};
#pragma unroll
  for (int nf = 0; nf < 4; nf++)
#pragma unroll
    for (int q = 0; q < 4; q++){ mst[nf][q] = -1e30f; lst[nf][q] = 0.f; }

#pragma unroll 1
  for (int mc = 0; mc < 4; mc++){
    f32x4 d[4][4] = {};
#pragma unroll
    for (int mj = 0; mj < 4; mj++)
#pragma unroll
      for (int ks = 0; ks < 2; ks++){
        bf16x8 kf = ld8(kb + (size_t)(bh*NTOK + mc*64 + mj*16 + l15)*TD + ks*32 + lg*8);
#pragma unroll
        for (int nf = 0; nf < 4; nf++) d[nf][mj] = mfma16(qf[nf][ks], kf, d[nf][mj]);
      }
#pragma unroll
    for (int nf = 0; nf < 4; nf++)
#pragma unroll
      for (int q = 0; q < 4; q++){
        float cm = fmaxf(fmaxf(d[nf][0][q], d[nf][1][q]), fmaxf(d[nf][2][q], d[nf][3][q]));
#pragma unroll
        for (int off = 1; off < 16; off <<= 1) cm = fmaxf(cm, __shfl_xor(cm, off, 64));
        float mnew = fmaxf(mst[nf][q], cm);
        float corr = __expf(mst[nf][q] - mnew);
        float rs = 0.f;
#pragma unroll
        for (int mj = 0; mj < 4; mj++){
          float e = __expf(d[nf][mj][q] - mnew);
          d[nf][mj][q] = e; rs += e;
        }
#pragma unroll
        for (int off = 1; off < 16; off <<= 1) rs += __shfl_xor(rs, off, 64);
        lst[nf][q] = lst[nf][q]*corr + rs;
        mst[nf][q] = mnew;
#pragma unroll
        for (int tf = 0; tf < 4; tf++) oac[nf][tf][q] *= corr;
        int nl = nf*16 + lg*4 + q;
#pragma unroll
        for (int mj = 0; mj < 4; mj++) pws[wave][nl][mj*16 + l15] = f2bf(d[nf][mj][q]);
      }
#pragma unroll
    for (int ks = 0; ks < 2; ks++){
      bf16x8 a[4];
#pragma unroll
      for (int nf = 0; nf < 4; nf++) a[nf] = ld8(&pws[wave][nf*16 + l15][ks*32 + lg*8]);
#pragma unroll
      for (int tf = 0; tf < 4; tf++){
        bf16x8 vf = ld8(vtb + (size_t)(bh*TD + tf*16 + l15)*NTOK + mc*64 + ks*32 + lg*8);
#pragma unroll
        for (int nf = 0; nf < 4; nf++) oac[nf][tf] = mfma16(a[nf], vf, oac[nf][tf]);
      }
    }
  }
#pragma unroll
  for (int nf = 0; nf < 4; nf++)
#pragma unroll
    for (int q = 0; q < 4; q++){
      float inv = 1.f / lst[nf][q];
      size_t row = (size_t)(b*NSEQ + n0 + nf*16 + lg*4 + q);
#pragma unroll
      for (int tf = 0; tf < 4; tf++)
        Wout[row*CD + h*TD + tf*16 + l15] = f2bf(oac[nf][tf][q] * inv);
    }
}

// ---------------- host ----------------
extern "C" void kernel_launch(void* const* d_in, const int* in_sizes, int n_in,
                              void* d_out, int out_size, void* d_ws, size_t ws_size,
                              hipStream_t stream){
  const float* W0     = (const float*)d_in[0];
  const float* Q      = (const float*)d_in[1];
  const float* kv1_w  = (const float*)d_in[2];
  const float* kv1_b  = (const float*)d_in[3];
  const float* qkv2_w = (const float*)d_in[4];
  const float* q3_w   = (const float*)d_in[5];
  const float* q3_b   = (const float*)d_in[6];
  const float* proj_w = (const float*)d_in[7];
  const float* proj_b = (const float*)d_in[8];
  (void)in_sizes; (void)n_in; (void)out_size; (void)ws_size;

  char* ws = (char*)d_ws;
  u16*   kv1_ws  = (u16*)  (ws);                                  // 32 MB bf16 (b,n,c)
  u16*   q3_ws   = (u16*)  (ws + ((size_t)32<<20));               // 32 MB
  u16*   W_ws    = (u16*)  (ws + ((size_t)64<<20));               // 32 MB
  float* o_part  = (float*)(ws + ((size_t)96<<20));               // 16 MB
  float* ml_part = (float*)(ws + ((size_t)112<<20));              // 0.5 MB
  u16*   kv1_wt  = (u16*)  (ws + ((size_t)113<<20));
  u16*   q3_wt   = (u16*)  (ws + ((size_t)113<<20) + (1<<20));
  u16*   proj_wt = (u16*)  (ws + ((size_t)113<<20) + (2<<20));
  u16*   Qb      = (u16*)  (ws + ((size_t)113<<20) + (3<<20));
  u16*   kb      = (u16*)  (ws + ((size_t)113<<20) + (4<<20));
  u16*   vtb     = (u16*)  (ws + ((size_t)113<<20) + (5<<20));    // total ~119 MB

  k_prep<<<1024, 256, 0, stream>>>(kv1_w, q3_w, proj_w, Q, kv1_wt, q3_wt, proj_wt, Qb);
  k_gemm512<1,0><<<dim3(256,4), 256, 0, stream>>>((const void*)W0, kv1_wt, kv1_b, 1.0f, (void*)kv1_ws);
  k_attn1<<<NB*NH*NSPLIT, 256, 0, stream>>>(kv1_ws, Qb, o_part, ml_part);
  k_comb<<<NB*NH, 256, 0, stream>>>(o_part, ml_part, qkv2_w, kb, vtb);
  k_gemm512<1,0><<<dim3(256,4), 256, 0, stream>>>((const void*)W0, q3_wt, q3_b, 0.125f, (void*)q3_ws);
  k_attn2<<<NB*NH*32, 256, 0, stream>>>(q3_ws, kb, vtb, W_ws);
  k_gemm512<0,1><<<dim3(256,4), 256, 0, stream>>>((const void*)W_ws, proj_wt, proj_b, 1.0f, (void*)d_out);
}

// Round 3
// 265.188 us; speedup vs baseline: 1.3722x; 1.3722x over previous
//
#include <hip/hip_runtime.h>
#include <hip/hip_bf16.h>

// GTO_Atten pipeline V3, MI355X (gfx950).
// Bisect round: GEMM staging reverted to proven ds_write path (bf16 A kept);
// attn1 m-split/occupancy structure and comb re-grid kept from V2.

#define NB 4
#define NSEQ 8192
#define CD 512
#define NH 8
#define TD 64
#define NTOK 256
#define NSPLIT 16
#define NKEYS (NSEQ / NSPLIT)   // 512 keys per split

typedef unsigned short u16;
typedef __bf16 bf16x8 __attribute__((ext_vector_type(8)));
typedef float f32x4 __attribute__((ext_vector_type(4)));

__device__ __forceinline__ u16 f2bf(float f){
  __hip_bfloat16 h = __float2bfloat16(f);
  u16 u; __builtin_memcpy(&u, &h, 2); return u;
}
__device__ __forceinline__ bf16x8 ld8(const u16* p){
  bf16x8 r; __builtin_memcpy(&r, p, 16); return r;
}
__device__ __forceinline__ f32x4 mfma16(bf16x8 a, bf16x8 b, f32x4 c){
  return __builtin_amdgcn_mfma_f32_16x16x32_bf16(a, b, c, 0, 0, 0);
}

// ---------------- K-1: W0 fp32 -> bf16 (flat copy) ----------------------------------
__global__ void k_cvt(const float* __restrict__ W0, u16* __restrict__ W0b){
  size_t i = (size_t)blockIdx.x * 256 + threadIdx.x;   // one float4 each; grid exact
  float4 v = ((const float4*)W0)[i];
  u16 w[4] = { f2bf(v.x), f2bf(v.y), f2bf(v.z), f2bf(v.w) };
  __builtin_memcpy(W0b + i*4, w, 8);
}

// ---------------- K0: prep (weights -> bf16 transposed [n][k]; Q,q3_w pre-scaled) ----
__global__ void k_prep(const float* __restrict__ kv1_w, const float* __restrict__ q3_w,
                       const float* __restrict__ proj_w, const float* __restrict__ Q,
                       u16* __restrict__ kv1_wt, u16* __restrict__ q3_wt,
                       u16* __restrict__ proj_wt, u16* __restrict__ Qb){
  int i = blockIdx.x * 256 + threadIdx.x;   // grid exact: CD*CD
  int k = i >> 9, n = i & 511;
  kv1_wt [n*CD + k] = f2bf(kv1_w[i]);
  q3_wt  [n*CD + k] = f2bf(q3_w[i] * 0.125f);   // fold 1/sqrt(td)
  proj_wt[n*CD + k] = f2bf(proj_w[i]);
  if (i < NH*NTOK*TD) Qb[i] = f2bf(Q[i] * 0.125f); // fold 1/sqrt(td)
}

// ---------------- GEMM: C[M][512] = A[M][512] @ B + bias; A bf16, Bt is [n][k] bf16 --
// Proven r1 staging: int4 global loads -> ds_write, pitch-72 LDS.
template<int OUT_F32>
__global__ __launch_bounds__(256, 2)
void k_gemm512(const u16* __restrict__ A, const u16* __restrict__ Bt,
               const float* __restrict__ bias, float bscale, void* __restrict__ outp){
  __shared__ __attribute__((aligned(16))) u16 As[128][72];
  __shared__ __attribute__((aligned(16))) u16 Bs[128][72];
  const int tid = threadIdx.x;
  const int lane = tid & 63, wave = tid >> 6;
  const int l15 = lane & 15, lg = lane >> 4;
  const int wm = (wave >> 1) * 64, wn = (wave & 1) * 64;
  const int bm = blockIdx.x, bn = blockIdx.y;
  f32x4 acc[4][4] = {};

#pragma unroll 1
  for (int k0 = 0; k0 < CD; k0 += 64){
    __syncthreads();
    {
      int r0 = tid >> 3, c8 = (tid & 7) << 3;
#pragma unroll
      for (int rr = 0; rr < 128; rr += 32){
        const u16* srcA = A  + (size_t)(bm*128 + r0 + rr) * CD + k0 + c8;
        int4 va = *(const int4*)srcA;
        __builtin_memcpy(&As[r0 + rr][c8], &va, 16);
        const u16* srcB = Bt + (size_t)(bn*128 + r0 + rr) * CD + k0 + c8;
        int4 vb = *(const int4*)srcB;
        __builtin_memcpy(&Bs[r0 + rr][c8], &vb, 16);
      }
    }
    __syncthreads();
#pragma unroll
    for (int ks = 0; ks < 2; ks++){
      bf16x8 af[4], bfr[4];
#pragma unroll
      for (int mf = 0; mf < 4; mf++) af[mf]  = ld8(&As[wm + mf*16 + l15][ks*32 + lg*8]);
#pragma unroll
      for (int nf = 0; nf < 4; nf++) bfr[nf] = ld8(&Bs[wn + nf*16 + l15][ks*32 + lg*8]);
#pragma unroll
      for (int mf = 0; mf < 4; mf++)
#pragma unroll
        for (int nf = 0; nf < 4; nf++)
          acc[mf][nf] = mfma16(af[mf], bfr[nf], acc[mf][nf]);
    }
  }
#pragma unroll
  for (int nf = 0; nf < 4; nf++){
    int col = bn*128 + wn + nf*16 + l15;
    float bv = bias[col] * bscale;
#pragma unroll
    for (int mf = 0; mf < 4; mf++){
      int row = bm*128 + wm + mf*16 + lg*4;
#pragma unroll
      for (int q = 0; q < 4; q++){
        float v = acc[mf][nf][q] + bv;
        if constexpr (OUT_F32) ((float*)outp)[(size_t)(row + q)*CD + col] = v;
        else                   ((u16*)outp)[(size_t)(row + q)*CD + col] = f2bf(v);
      }
    }
  }
}

// ---------------- K2: attn1 partial flash (m-split x n-split) -----------------------
// grid (32 bh, 2 mt, 16 s); each wave owns 32 m-rows. LDS 36.9KB -> 4 blocks/CU.
__global__ __launch_bounds__(256, 4)
void k_attn1(const u16* __restrict__ kv1, const u16* __restrict__ Qb,
             float* __restrict__ o_part, float* __restrict__ ml_part){
  __shared__ __attribute__((aligned(16))) u16 kvs[64][72];    // [n][td]
  __shared__ __attribute__((aligned(16))) u16 kvts[64][72];   // [td][n]
  __shared__ __attribute__((aligned(16))) u16 pws[4][32][72]; // per-wave P [m][n]
  const int tid = threadIdx.x, lane = tid & 63, wave = tid >> 6;
  const int bh = blockIdx.x, mt = blockIdx.y, s = blockIdx.z;
  const int b = bh >> 3, h = bh & 7;
  const int l15 = lane & 15, lg = lane >> 4;
  const int m0 = mt*128 + wave*32;

  bf16x8 qf[2][2];
#pragma unroll
  for (int mf = 0; mf < 2; mf++)
#pragma unroll
    for (int ks = 0; ks < 2; ks++)
      qf[mf][ks] = ld8(Qb + (size_t)(h*NTOK + m0 + mf*16 + l15)*TD + ks*32 + lg*8);

  float mst[2][4], lst[2][4];
  f32x4 oac[2][4] = {};
#pragma unroll
  for (int mf = 0; mf < 2; mf++)
#pragma unroll
    for (int q = 0; q < 4; q++){ mst[mf][q] = -1e30f; lst[mf][q] = 0.f; }

#pragma unroll 1
  for (int c = 0; c < NKEYS/64; c++){
    const int nc = s*NKEYS + c*64;
    __syncthreads();
    {
      int r = tid >> 2, seg = (tid & 3) * 16;
      const u16* src = kv1 + (size_t)(b*NSEQ + nc + r)*CD + h*TD + seg;
      int4 v0 = *(const int4*)src;
      int4 v1 = *(const int4*)(src + 8);
      __builtin_memcpy(&kvs[r][seg],     &v0, 16);
      __builtin_memcpy(&kvs[r][seg + 8], &v1, 16);
      u16 tmp[16];
      __builtin_memcpy(tmp,     &v0, 16);
      __builtin_memcpy(tmp + 8, &v1, 16);
#pragma unroll
      for (int j = 0; j < 16; j++) kvts[seg + j][r] = tmp[j];
    }
    __syncthreads();
    f32x4 d[2][4] = {};
#pragma unroll
    for (int nf = 0; nf < 4; nf++)
#pragma unroll
      for (int ks = 0; ks < 2; ks++){
        bf16x8 kf = ld8(&kvs[nf*16 + l15][ks*32 + lg*8]);
#pragma unroll
        for (int mf = 0; mf < 2; mf++) d[mf][nf] = mfma16(qf[mf][ks], kf, d[mf][nf]);
      }
#pragma unroll
    for (int mf = 0; mf < 2; mf++)
#pragma unroll
      for (int q = 0; q < 4; q++){
        float cm = fmaxf(fmaxf(d[mf][0][q], d[mf][1][q]), fmaxf(d[mf][2][q], d[mf][3][q]));
#pragma unroll
        for (int off = 1; off < 16; off <<= 1) cm = fmaxf(cm, __shfl_xor(cm, off, 64));
        float mnew = fmaxf(mst[mf][q], cm);
        float corr = __expf(mst[mf][q] - mnew);
        float rs = 0.f;
#pragma unroll
        for (int nf = 0; nf < 4; nf++){
          float e = __expf(d[mf][nf][q] - mnew);
          d[mf][nf][q] = e; rs += e;
        }
#pragma unroll
        for (int off = 1; off < 16; off <<= 1) rs += __shfl_xor(rs, off, 64);
        lst[mf][q] = lst[mf][q]*corr + rs;
        mst[mf][q] = mnew;
#pragma unroll
        for (int tf = 0; tf < 4; tf++) oac[mf][tf][q] *= corr;
        int ml = mf*16 + lg*4 + q;
#pragma unroll
        for (int nf = 0; nf < 4; nf++) pws[wave][ml][nf*16 + l15] = f2bf(d[mf][nf][q]);
      }
#pragma unroll
    for (int ks = 0; ks < 2; ks++){
      bf16x8 a[2];
#pragma unroll
      for (int mf = 0; mf < 2; mf++) a[mf] = ld8(&pws[wave][mf*16 + l15][ks*32 + lg*8]);
#pragma unroll
      for (int tf = 0; tf < 4; tf++){
        bf16x8 vf = ld8(&kvts[tf*16 + l15][ks*32 + lg*8]);
#pragma unroll
        for (int mf = 0; mf < 2; mf++) oac[mf][tf] = mfma16(a[mf], vf, oac[mf][tf]);
      }
    }
  }
  const size_t pbase = (size_t)(bh*NSPLIT + s);
#pragma unroll
  for (int mf = 0; mf < 2; mf++)
#pragma unroll
    for (int q = 0; q < 4; q++){
      int m = m0 + mf*16 + lg*4 + q;
#pragma unroll
      for (int tf = 0; tf < 4; tf++)
        o_part[(pbase*NTOK + m)*TD + tf*16 + l15] = oac[mf][tf][q];
      if (l15 == 0){
        ml_part[(pbase*2)*NTOK + m]     = mst[mf][q];
        ml_part[(pbase*2 + 1)*NTOK + m] = lst[mf][q];
      }
    }
}

// ---------------- K3: combine partials + kv2 GEMM -----------------------------------
// grid 512 = bh(32) x mtile(16); 16 m-rows/block.
__global__ __launch_bounds__(256, 2)
void k_comb(const float* __restrict__ o_part, const float* __restrict__ ml_part,
            const float* __restrict__ qkv2_w, u16* __restrict__ kb, u16* __restrict__ vtb){
  __shared__ float w2[TD*2*TD];       // 32KB
  __shared__ float osh[16][68];
  const int tid = threadIdx.x;
  const int bh = blockIdx.x >> 4, mtile = blockIdx.x & 15;
  const int m0 = mtile * 16;
  for (int i = tid; i < TD*2*TD/4; i += 256) ((float4*)w2)[i] = ((const float4*)qkv2_w)[i];

  const int mi = tid >> 4, tj = tid & 15;
  const int m = m0 + mi;
  float M = -1e30f;
#pragma unroll
  for (int s = 0; s < NSPLIT; s++)
    M = fmaxf(M, ml_part[(size_t)((bh*NSPLIT + s)*2)*NTOK + m]);
  float4 acc = make_float4(0.f,0.f,0.f,0.f);
  float denom = 0.f;
#pragma unroll 1
  for (int s = 0; s < NSPLIT; s++){
    size_t base = (size_t)(bh*NSPLIT + s);
    float w = __expf(ml_part[(base*2)*NTOK + m] - M);
    denom += ml_part[(base*2 + 1)*NTOK + m] * w;
    float4 v = ((const float4*)(o_part + (base*NTOK + m)*TD))[tj];
    acc.x += w*v.x; acc.y += w*v.y; acc.z += w*v.z; acc.w += w*v.w;
  }
  float inv = 1.f / denom;
  osh[mi][tj*4+0] = acc.x*inv; osh[mi][tj*4+1] = acc.y*inv;
  osh[mi][tj*4+2] = acc.z*inv; osh[mi][tj*4+3] = acc.w*inv;
  __syncthreads();
  const int j0 = tj * 8;
  float o8[8] = {};
#pragma unroll
  for (int t = 0; t < TD; t++){
    float ov = osh[mi][t];
#pragma unroll
    for (int jj = 0; jj < 8; jj++) o8[jj] += ov * w2[t*2*TD + j0 + jj];
  }
  if (j0 < TD){
#pragma unroll
    for (int jj = 0; jj < 8; jj++)
      kb[(size_t)(bh*NTOK + m)*TD + j0 + jj] = f2bf(o8[jj]);
  } else {
#pragma unroll
    for (int jj = 0; jj < 8; jj++)
      vtb[(size_t)(bh*TD + (j0 - TD + jj))*NTOK + m] = f2bf(o8[jj]);
  }
}

// ---------------- K5: attn2 (softmax over m=256, fully local) ----------------------
__global__ __launch_bounds__(256, 2)
void k_attn2(const u16* __restrict__ q3, const u16* __restrict__ kb,
             const u16* __restrict__ vtb, u16* __restrict__ Wout){
  __shared__ __attribute__((aligned(16))) u16 pws[4][64][72];
  const int tid = threadIdx.x, lane = tid & 63, wave = tid >> 6;
  const int blk = blockIdx.x;           // bh*32 + nt
  const int bh = blk >> 5, nt = blk & 31;
  const int b = bh >> 3, h = bh & 7;
  const int l15 = lane & 15, lg = lane >> 4;
  const int n0 = nt * 256 + wave * 64;

  bf16x8 qf[4][2];
#pragma unroll
  for (int nf = 0; nf < 4; nf++)
#pragma unroll
    for (int ks = 0; ks < 2; ks++)
      qf[nf][ks] = ld8(q3 + (size_t)(b*NSEQ + n0 + nf*16 + l15)*CD + h*TD + ks*32 + lg*8);

  float mst[4][4], lst[4][4];
  f32x4 oac[4][4] = {};
#pragma unroll
  for (int nf = 0; nf < 4; nf++)
#pragma unroll
    for (int q = 0; q < 4; q++){ mst[nf][q] = -1e30f; lst[nf][q] = 0.f; }

#pragma unroll 1
  for (int mc = 0; mc < 4; mc++){
    f32x4 d[4][4] = {};
#pragma unroll
    for (int mj = 0; mj < 4; mj++)
#pragma unroll
      for (int ks = 0; ks < 2; ks++){
        bf16x8 kf = ld8(kb + (size_t)(bh*NTOK + mc*64 + mj*16 + l15)*TD + ks*32 + lg*8);
#pragma unroll
        for (int nf = 0; nf < 4; nf++) d[nf][mj] = mfma16(qf[nf][ks], kf, d[nf][mj]);
      }
#pragma unroll
    for (int nf = 0; nf < 4; nf++)
#pragma unroll
      for (int q = 0; q < 4; q++){
        float cm = fmaxf(fmaxf(d[nf][0][q], d[nf][1][q]), fmaxf(d[nf][2][q], d[nf][3][q]));
#pragma unroll
        for (int off = 1; off < 16; off <<= 1) cm = fmaxf(cm, __shfl_xor(cm, off, 64));
        float mnew = fmaxf(mst[nf][q], cm);
        float corr = __expf(mst[nf][q] - mnew);
        float rs = 0.f;
#pragma unroll
        for (int mj = 0; mj < 4; mj++){
          float e = __expf(d[nf][mj][q] - mnew);
          d[nf][mj][q] = e; rs += e;
        }
#pragma unroll
        for (int off = 1; off < 16; off <<= 1) rs += __shfl_xor(rs, off, 64);
        lst[nf][q] = lst[nf][q]*corr + rs;
        mst[nf][q] = mnew;
#pragma unroll
        for (int tf = 0; tf < 4; tf++) oac[nf][tf][q] *= corr;
        int nl = nf*16 + lg*4 + q;
#pragma unroll
        for (int mj = 0; mj < 4; mj++) pws[wave][nl][mj*16 + l15] = f2bf(d[nf][mj][q]);
      }
#pragma unroll
    for (int ks = 0; ks < 2; ks++){
      bf16x8 a[4];
#pragma unroll
      for (int nf = 0; nf < 4; nf++) a[nf] = ld8(&pws[wave][nf*16 + l15][ks*32 + lg*8]);
#pragma unroll
      for (int tf = 0; tf < 4; tf++){
        bf16x8 vf = ld8(vtb + (size_t)(bh*TD + tf*16 + l15)*NTOK + mc*64 + ks*32 + lg*8);
#pragma unroll
        for (int nf = 0; nf < 4; nf++) oac[nf][tf] = mfma16(a[nf], vf, oac[nf][tf]);
      }
    }
  }
#pragma unroll
  for (int nf = 0; nf < 4; nf++)
#pragma unroll
    for (int q = 0; q < 4; q++){
      float inv = 1.f / lst[nf][q];
      size_t row = (size_t)(b*NSEQ + n0 + nf*16 + lg*4 + q);
#pragma unroll
      for (int tf = 0; tf < 4; tf++)
        Wout[row*CD + h*TD + tf*16 + l15] = f2bf(oac[nf][tf][q] * inv);
    }
}

// ---------------- host ----------------
extern "C" void kernel_launch(void* const* d_in, const int* in_sizes, int n_in,
                              void* d_out, int out_size, void* d_ws, size_t ws_size,
                              hipStream_t stream){
  const float* W0     = (const float*)d_in[0];
  const float* Q      = (const float*)d_in[1];
  const float* kv1_w  = (const float*)d_in[2];
  const float* kv1_b  = (const float*)d_in[3];
  const float* qkv2_w = (const float*)d_in[4];
  const float* q3_w   = (const float*)d_in[5];
  const float* q3_b   = (const float*)d_in[6];
  const float* proj_w = (const float*)d_in[7];
  const float* proj_b = (const float*)d_in[8];
  (void)in_sizes; (void)n_in; (void)out_size; (void)ws_size;

  char* ws = (char*)d_ws;
  u16*   W0b     = (u16*)  (ws);                                  // [0,32MiB)
  u16*   kv1_ws  = (u16*)  (ws + ((size_t)32<<20));               // [32,64) -> later W_ws
  float* o_part  = (float*)(ws + ((size_t)64<<20));               // [64,96) -> later q3_ws
  float* ml_part = (float*)(ws + ((size_t)96<<20));               // [96,97)
  u16*   kv1_wt  = (u16*)  (ws + ((size_t)97<<20));               // 512 KiB
  u16*   q3_wt   = (u16*)  (ws + ((size_t)97<<20) + (1<<19));     // 512 KiB
  u16*   proj_wt = (u16*)  (ws + ((size_t)98<<20));               // 512 KiB
  u16*   Qb      = (u16*)  (ws + ((size_t)98<<20) + (1<<19));     // 256 KiB
  u16*   kb      = (u16*)  (ws + ((size_t)99<<20));               // 1 MiB
  u16*   vtb     = (u16*)  (ws + ((size_t)100<<20));              // 1 MiB; total ~101 MiB
  u16*   q3_ws   = (u16*)  (ws + ((size_t)64<<20));               // alias o_part
  u16*   W_ws    = (u16*)  (ws + ((size_t)32<<20));               // alias kv1_ws

  k_cvt<<<16384, 256, 0, stream>>>(W0, W0b);
  k_prep<<<1024, 256, 0, stream>>>(kv1_w, q3_w, proj_w, Q, kv1_wt, q3_wt, proj_wt, Qb);
  k_gemm512<0><<<dim3(256,4), 256, 0, stream>>>(W0b, kv1_wt, kv1_b, 1.0f, (void*)kv1_ws);
  k_attn1<<<dim3(NB*NH, 2, NSPLIT), 256, 0, stream>>>(kv1_ws, Qb, o_part, ml_part);
  k_comb<<<NB*NH*16, 256, 0, stream>>>(o_part, ml_part, qkv2_w, kb, vtb);
  k_gemm512<0><<<dim3(256,4), 256, 0, stream>>>(W0b, q3_wt, q3_b, 0.125f, (void*)q3_ws);
  k_attn2<<<NB*NH*32, 256, 0, stream>>>(q3_ws, kb, vtb, W_ws);
  k_gemm512<1><<<dim3(256,4), 256, 0, stream>>>(W_ws, proj_wt, proj_b, 1.0f, (void*)d_out);
}

// Round 4
// 264.097 us; speedup vs baseline: 1.3779x; 1.0041x over previous
//
#include <hip/hip_runtime.h>
#include <hip/hip_bf16.h>

// GTO_Atten pipeline V4, MI355X (gfx950).
// V3 + attn2 rewritten: single-pass softmax (full 256-key row in registers),
// 32 queries/wave, one butterfly reduce per row. Everything else unchanged.

#define NB 4
#define NSEQ 8192
#define CD 512
#define NH 8
#define TD 64
#define NTOK 256
#define NSPLIT 16
#define NKEYS (NSEQ / NSPLIT)   // 512 keys per split

typedef unsigned short u16;
typedef __bf16 bf16x8 __attribute__((ext_vector_type(8)));
typedef float f32x4 __attribute__((ext_vector_type(4)));

__device__ __forceinline__ u16 f2bf(float f){
  __hip_bfloat16 h = __float2bfloat16(f);
  u16 u; __builtin_memcpy(&u, &h, 2); return u;
}
__device__ __forceinline__ bf16x8 ld8(const u16* p){
  bf16x8 r; __builtin_memcpy(&r, p, 16); return r;
}
__device__ __forceinline__ f32x4 mfma16(bf16x8 a, bf16x8 b, f32x4 c){
  return __builtin_amdgcn_mfma_f32_16x16x32_bf16(a, b, c, 0, 0, 0);
}

// ---------------- K-1: W0 fp32 -> bf16 (flat copy) ----------------------------------
__global__ void k_cvt(const float* __restrict__ W0, u16* __restrict__ W0b){
  size_t i = (size_t)blockIdx.x * 256 + threadIdx.x;   // one float4 each; grid exact
  float4 v = ((const float4*)W0)[i];
  u16 w[4] = { f2bf(v.x), f2bf(v.y), f2bf(v.z), f2bf(v.w) };
  __builtin_memcpy(W0b + i*4, w, 8);
}

// ---------------- K0: prep (weights -> bf16 transposed [n][k]; Q,q3_w pre-scaled) ----
__global__ void k_prep(const float* __restrict__ kv1_w, const float* __restrict__ q3_w,
                       const float* __restrict__ proj_w, const float* __restrict__ Q,
                       u16* __restrict__ kv1_wt, u16* __restrict__ q3_wt,
                       u16* __restrict__ proj_wt, u16* __restrict__ Qb){
  int i = blockIdx.x * 256 + threadIdx.x;   // grid exact: CD*CD
  int k = i >> 9, n = i & 511;
  kv1_wt [n*CD + k] = f2bf(kv1_w[i]);
  q3_wt  [n*CD + k] = f2bf(q3_w[i] * 0.125f);   // fold 1/sqrt(td)
  proj_wt[n*CD + k] = f2bf(proj_w[i]);
  if (i < NH*NTOK*TD) Qb[i] = f2bf(Q[i] * 0.125f); // fold 1/sqrt(td)
}

// ---------------- GEMM: C[M][512] = A[M][512] @ B + bias; A bf16, Bt is [n][k] bf16 --
template<int OUT_F32>
__global__ __launch_bounds__(256, 2)
void k_gemm512(const u16* __restrict__ A, const u16* __restrict__ Bt,
               const float* __restrict__ bias, float bscale, void* __restrict__ outp){
  __shared__ __attribute__((aligned(16))) u16 As[128][72];
  __shared__ __attribute__((aligned(16))) u16 Bs[128][72];
  const int tid = threadIdx.x;
  const int lane = tid & 63, wave = tid >> 6;
  const int l15 = lane & 15, lg = lane >> 4;
  const int wm = (wave >> 1) * 64, wn = (wave & 1) * 64;
  const int bm = blockIdx.x, bn = blockIdx.y;
  f32x4 acc[4][4] = {};

#pragma unroll 1
  for (int k0 = 0; k0 < CD; k0 += 64){
    __syncthreads();
    {
      int r0 = tid >> 3, c8 = (tid & 7) << 3;
#pragma unroll
      for (int rr = 0; rr < 128; rr += 32){
        const u16* srcA = A  + (size_t)(bm*128 + r0 + rr) * CD + k0 + c8;
        int4 va = *(const int4*)srcA;
        __builtin_memcpy(&As[r0 + rr][c8], &va, 16);
        const u16* srcB = Bt + (size_t)(bn*128 + r0 + rr) * CD + k0 + c8;
        int4 vb = *(const int4*)srcB;
        __builtin_memcpy(&Bs[r0 + rr][c8], &vb, 16);
      }
    }
    __syncthreads();
#pragma unroll
    for (int ks = 0; ks < 2; ks++){
      bf16x8 af[4], bfr[4];
#pragma unroll
      for (int mf = 0; mf < 4; mf++) af[mf]  = ld8(&As[wm + mf*16 + l15][ks*32 + lg*8]);
#pragma unroll
      for (int nf = 0; nf < 4; nf++) bfr[nf] = ld8(&Bs[wn + nf*16 + l15][ks*32 + lg*8]);
#pragma unroll
      for (int mf = 0; mf < 4; mf++)
#pragma unroll
        for (int nf = 0; nf < 4; nf++)
          acc[mf][nf] = mfma16(af[mf], bfr[nf], acc[mf][nf]);
    }
  }
#pragma unroll
  for (int nf = 0; nf < 4; nf++){
    int col = bn*128 + wn + nf*16 + l15;
    float bv = bias[col] * bscale;
#pragma unroll
    for (int mf = 0; mf < 4; mf++){
      int row = bm*128 + wm + mf*16 + lg*4;
#pragma unroll
      for (int q = 0; q < 4; q++){
        float v = acc[mf][nf][q] + bv;
        if constexpr (OUT_F32) ((float*)outp)[(size_t)(row + q)*CD + col] = v;
        else                   ((u16*)outp)[(size_t)(row + q)*CD + col] = f2bf(v);
      }
    }
  }
}

// ---------------- K2: attn1 partial flash (m-split x n-split) -----------------------
__global__ __launch_bounds__(256, 4)
void k_attn1(const u16* __restrict__ kv1, const u16* __restrict__ Qb,
             float* __restrict__ o_part, float* __restrict__ ml_part){
  __shared__ __attribute__((aligned(16))) u16 kvs[64][72];    // [n][td]
  __shared__ __attribute__((aligned(16))) u16 kvts[64][72];   // [td][n]
  __shared__ __attribute__((aligned(16))) u16 pws[4][32][72]; // per-wave P [m][n]
  const int tid = threadIdx.x, lane = tid & 63, wave = tid >> 6;
  const int bh = blockIdx.x, mt = blockIdx.y, s = blockIdx.z;
  const int b = bh >> 3, h = bh & 7;
  const int l15 = lane & 15, lg = lane >> 4;
  const int m0 = mt*128 + wave*32;

  bf16x8 qf[2][2];
#pragma unroll
  for (int mf = 0; mf < 2; mf++)
#pragma unroll
    for (int ks = 0; ks < 2; ks++)
      qf[mf][ks] = ld8(Qb + (size_t)(h*NTOK + m0 + mf*16 + l15)*TD + ks*32 + lg*8);

  float mst[2][4], lst[2][4];
  f32x4 oac[2][4] = {};
#pragma unroll
  for (int mf = 0; mf < 2; mf++)
#pragma unroll
    for (int q = 0; q < 4; q++){ mst[mf][q] = -1e30f; lst[mf][q] = 0.f; }

#pragma unroll 1
  for (int c = 0; c < NKEYS/64; c++){
    const int nc = s*NKEYS + c*64;
    __syncthreads();
    {
      int r = tid >> 2, seg = (tid & 3) * 16;
      const u16* src = kv1 + (size_t)(b*NSEQ + nc + r)*CD + h*TD + seg;
      int4 v0 = *(const int4*)src;
      int4 v1 = *(const int4*)(src + 8);
      __builtin_memcpy(&kvs[r][seg],     &v0, 16);
      __builtin_memcpy(&kvs[r][seg + 8], &v1, 16);
      u16 tmp[16];
      __builtin_memcpy(tmp,     &v0, 16);
      __builtin_memcpy(tmp + 8, &v1, 16);
#pragma unroll
      for (int j = 0; j < 16; j++) kvts[seg + j][r] = tmp[j];
    }
    __syncthreads();
    f32x4 d[2][4] = {};
#pragma unroll
    for (int nf = 0; nf < 4; nf++)
#pragma unroll
      for (int ks = 0; ks < 2; ks++){
        bf16x8 kf = ld8(&kvs[nf*16 + l15][ks*32 + lg*8]);
#pragma unroll
        for (int mf = 0; mf < 2; mf++) d[mf][nf] = mfma16(qf[mf][ks], kf, d[mf][nf]);
      }
#pragma unroll
    for (int mf = 0; mf < 2; mf++)
#pragma unroll
      for (int q = 0; q < 4; q++){
        float cm = fmaxf(fmaxf(d[mf][0][q], d[mf][1][q]), fmaxf(d[mf][2][q], d[mf][3][q]));
#pragma unroll
        for (int off = 1; off < 16; off <<= 1) cm = fmaxf(cm, __shfl_xor(cm, off, 64));
        float mnew = fmaxf(mst[mf][q], cm);
        float corr = __expf(mst[mf][q] - mnew);
        float rs = 0.f;
#pragma unroll
        for (int nf = 0; nf < 4; nf++){
          float e = __expf(d[mf][nf][q] - mnew);
          d[mf][nf][q] = e; rs += e;
        }
#pragma unroll
        for (int off = 1; off < 16; off <<= 1) rs += __shfl_xor(rs, off, 64);
        lst[mf][q] = lst[mf][q]*corr + rs;
        mst[mf][q] = mnew;
#pragma unroll
        for (int tf = 0; tf < 4; tf++) oac[mf][tf][q] *= corr;
        int ml = mf*16 + lg*4 + q;
#pragma unroll
        for (int nf = 0; nf < 4; nf++) pws[wave][ml][nf*16 + l15] = f2bf(d[mf][nf][q]);
      }
#pragma unroll
    for (int ks = 0; ks < 2; ks++){
      bf16x8 a[2];
#pragma unroll
      for (int mf = 0; mf < 2; mf++) a[mf] = ld8(&pws[wave][mf*16 + l15][ks*32 + lg*8]);
#pragma unroll
      for (int tf = 0; tf < 4; tf++){
        bf16x8 vf = ld8(&kvts[tf*16 + l15][ks*32 + lg*8]);
#pragma unroll
        for (int mf = 0; mf < 2; mf++) oac[mf][tf] = mfma16(a[mf], vf, oac[mf][tf]);
      }
    }
  }
  const size_t pbase = (size_t)(bh*NSPLIT + s);
#pragma unroll
  for (int mf = 0; mf < 2; mf++)
#pragma unroll
    for (int q = 0; q < 4; q++){
      int m = m0 + mf*16 + lg*4 + q;
#pragma unroll
      for (int tf = 0; tf < 4; tf++)
        o_part[(pbase*NTOK + m)*TD + tf*16 + l15] = oac[mf][tf][q];
      if (l15 == 0){
        ml_part[(pbase*2)*NTOK + m]     = mst[mf][q];
        ml_part[(pbase*2 + 1)*NTOK + m] = lst[mf][q];
      }
    }
}

// ---------------- K3: combine partials + kv2 GEMM -----------------------------------
__global__ __launch_bounds__(256, 2)
void k_comb(const float* __restrict__ o_part, const float* __restrict__ ml_part,
            const float* __restrict__ qkv2_w, u16* __restrict__ kb, u16* __restrict__ vtb){
  __shared__ float w2[TD*2*TD];       // 32KB
  __shared__ float osh[16][68];
  const int tid = threadIdx.x;
  const int bh = blockIdx.x >> 4, mtile = blockIdx.x & 15;
  const int m0 = mtile * 16;
  for (int i = tid; i < TD*2*TD/4; i += 256) ((float4*)w2)[i] = ((const float4*)qkv2_w)[i];

  const int mi = tid >> 4, tj = tid & 15;
  const int m = m0 + mi;
  float M = -1e30f;
#pragma unroll
  for (int s = 0; s < NSPLIT; s++)
    M = fmaxf(M, ml_part[(size_t)((bh*NSPLIT + s)*2)*NTOK + m]);
  float4 acc = make_float4(0.f,0.f,0.f,0.f);
  float denom = 0.f;
#pragma unroll 1
  for (int s = 0; s < NSPLIT; s++){
    size_t base = (size_t)(bh*NSPLIT + s);
    float w = __expf(ml_part[(base*2)*NTOK + m] - M);
    denom += ml_part[(base*2 + 1)*NTOK + m] * w;
    float4 v = ((const float4*)(o_part + (base*NTOK + m)*TD))[tj];
    acc.x += w*v.x; acc.y += w*v.y; acc.z += w*v.z; acc.w += w*v.w;
  }
  float inv = 1.f / denom;
  osh[mi][tj*4+0] = acc.x*inv; osh[mi][tj*4+1] = acc.y*inv;
  osh[mi][tj*4+2] = acc.z*inv; osh[mi][tj*4+3] = acc.w*inv;
  __syncthreads();
  const int j0 = tj * 8;
  float o8[8] = {};
#pragma unroll
  for (int t = 0; t < TD; t++){
    float ov = osh[mi][t];
#pragma unroll
    for (int jj = 0; jj < 8; jj++) o8[jj] += ov * w2[t*2*TD + j0 + jj];
  }
  if (j0 < TD){
#pragma unroll
    for (int jj = 0; jj < 8; jj++)
      kb[(size_t)(bh*NTOK + m)*TD + j0 + jj] = f2bf(o8[jj]);
  } else {
#pragma unroll
    for (int jj = 0; jj < 8; jj++)
      vtb[(size_t)(bh*TD + (j0 - TD + jj))*NTOK + m] = f2bf(o8[jj]);
  }
}

// ---------------- K5: attn2 V4 — single-pass softmax, 32 queries/wave ---------------
// Per wave: full 256-key logit row in regs (d[2][16] f32x4), one butterfly reduce,
// P -> per-wave LDS (pitch 264), PV from LDS A-frags x vtb B-frags.
__global__ __launch_bounds__(256, 2)
void k_attn2(const u16* __restrict__ q3, const u16* __restrict__ kb,
             const u16* __restrict__ vtb, u16* __restrict__ Wout){
  __shared__ __attribute__((aligned(16))) u16 pws[4][32][264];  // 66KB
  const int tid = threadIdx.x, lane = tid & 63, wave = tid >> 6;
  const int bh = blockIdx.x >> 6, nt = blockIdx.x & 63;
  const int b = bh >> 3, h = bh & 7;
  const int l15 = lane & 15, lg = lane >> 4;
  const int n0 = nt * 128 + wave * 32;

  // A-frags of q3 (pre-scaled by 1/8 in GEMM): rows n0..n0+31
  bf16x8 qf[2][2];
#pragma unroll
  for (int mf = 0; mf < 2; mf++)
#pragma unroll
    for (int ks = 0; ks < 2; ks++)
      qf[mf][ks] = ld8(q3 + (size_t)(b*NSEQ + n0 + mf*16 + l15)*CD + h*TD + ks*32 + lg*8);

  // QK^T: all 256 keys, logits stay in registers
  f32x4 d[2][16] = {};
#pragma unroll
  for (int nf = 0; nf < 16; nf++){
    const u16* kp = kb + (size_t)(bh*NTOK + nf*16 + l15)*TD + lg*8;
    bf16x8 b0 = ld8(kp);
    bf16x8 b1 = ld8(kp + 32);
    d[0][nf] = mfma16(qf[0][0], b0, d[0][nf]);
    d[0][nf] = mfma16(qf[0][1], b1, d[0][nf]);
    d[1][nf] = mfma16(qf[1][0], b0, d[1][nf]);
    d[1][nf] = mfma16(qf[1][1], b1, d[1][nf]);
  }

  // single-pass softmax per row (row = mf*16 + lg*4 + q; keys = nf*16 + l15)
  float rsum[2][4];
#pragma unroll
  for (int mf = 0; mf < 2; mf++)
#pragma unroll
    for (int q = 0; q < 4; q++){
      float m = d[mf][0][q];
#pragma unroll
      for (int nf = 1; nf < 16; nf++) m = fmaxf(m, d[mf][nf][q]);
#pragma unroll
      for (int off = 1; off < 16; off <<= 1) m = fmaxf(m, __shfl_xor(m, off, 64));
      float rs = 0.f;
#pragma unroll
      for (int nf = 0; nf < 16; nf++){
        float e = __expf(d[mf][nf][q] - m);
        d[mf][nf][q] = e; rs += e;
      }
#pragma unroll
      for (int off = 1; off < 16; off <<= 1) rs += __shfl_xor(rs, off, 64);
      rsum[mf][q] = rs;
      int rl = mf*16 + lg*4 + q;
#pragma unroll
      for (int nf = 0; nf < 16; nf++) pws[wave][rl][nf*16 + l15] = f2bf(d[mf][nf][q]);
    }

  // PV: O[32 q][64 td] = P (LDS A-frags) x V (vtb [td][key] B-frags), sum over 256 keys
  f32x4 oac[2][4] = {};
#pragma unroll
  for (int ks = 0; ks < 8; ks++){
    bf16x8 a0 = ld8(&pws[wave][l15][ks*32 + lg*8]);
    bf16x8 a1 = ld8(&pws[wave][16 + l15][ks*32 + lg*8]);
#pragma unroll
    for (int tf = 0; tf < 4; tf++){
      bf16x8 vf = ld8(vtb + (size_t)(bh*TD + tf*16 + l15)*NTOK + ks*32 + lg*8);
      oac[0][tf] = mfma16(a0, vf, oac[0][tf]);
      oac[1][tf] = mfma16(a1, vf, oac[1][tf]);
    }
  }

#pragma unroll
  for (int mf = 0; mf < 2; mf++)
#pragma unroll
    for (int q = 0; q < 4; q++){
      float inv = 1.f / rsum[mf][q];
      size_t row = (size_t)(b*NSEQ + n0 + mf*16 + lg*4 + q);
#pragma unroll
      for (int tf = 0; tf < 4; tf++)
        Wout[row*CD + h*TD + tf*16 + l15] = f2bf(oac[mf][tf][q] * inv);
    }
}

// ---------------- host ----------------
extern "C" void kernel_launch(void* const* d_in, const int* in_sizes, int n_in,
                              void* d_out, int out_size, void* d_ws, size_t ws_size,
                              hipStream_t stream){
  const float* W0     = (const float*)d_in[0];
  const float* Q      = (const float*)d_in[1];
  const float* kv1_w  = (const float*)d_in[2];
  const float* kv1_b  = (const float*)d_in[3];
  const float* qkv2_w = (const float*)d_in[4];
  const float* q3_w   = (const float*)d_in[5];
  const float* q3_b   = (const float*)d_in[6];
  const float* proj_w = (const float*)d_in[7];
  const float* proj_b = (const float*)d_in[8];
  (void)in_sizes; (void)n_in; (void)out_size; (void)ws_size;

  char* ws = (char*)d_ws;
  u16*   W0b     = (u16*)  (ws);                                  // [0,32MiB)
  u16*   kv1_ws  = (u16*)  (ws + ((size_t)32<<20));               // [32,64) -> later W_ws
  float* o_part  = (float*)(ws + ((size_t)64<<20));               // [64,96) -> later q3_ws
  float* ml_part = (float*)(ws + ((size_t)96<<20));               // [96,97)
  u16*   kv1_wt  = (u16*)  (ws + ((size_t)97<<20));               // 512 KiB
  u16*   q3_wt   = (u16*)  (ws + ((size_t)97<<20) + (1<<19));     // 512 KiB
  u16*   proj_wt = (u16*)  (ws + ((size_t)98<<20));               // 512 KiB
  u16*   Qb      = (u16*)  (ws + ((size_t)98<<20) + (1<<19));     // 256 KiB
  u16*   kb      = (u16*)  (ws + ((size_t)99<<20));               // 1 MiB
  u16*   vtb     = (u16*)  (ws + ((size_t)100<<20));              // 1 MiB; total ~101 MiB
  u16*   q3_ws   = (u16*)  (ws + ((size_t)64<<20));               // alias o_part
  u16*   W_ws    = (u16*)  (ws + ((size_t)32<<20));               // alias kv1_ws

  k_cvt<<<16384, 256, 0, stream>>>(W0, W0b);
  k_prep<<<1024, 256, 0, stream>>>(kv1_w, q3_w, proj_w, Q, kv1_wt, q3_wt, proj_wt, Qb);
  k_gemm512<0><<<dim3(256,4), 256, 0, stream>>>(W0b, kv1_wt, kv1_b, 1.0f, (void*)kv1_ws);
  k_attn1<<<dim3(NB*NH, 2, NSPLIT), 256, 0, stream>>>(kv1_ws, Qb, o_part, ml_part);
  k_comb<<<NB*NH*16, 256, 0, stream>>>(o_part, ml_part, qkv2_w, kb, vtb);
  k_gemm512<0><<<dim3(256,4), 256, 0, stream>>>(W0b, q3_wt, q3_b, 0.125f, (void*)q3_ws);
  k_attn2<<<NB*NH*64, 256, 0, stream>>>(q3_ws, kb, vtb, W_ws);
  k_gemm512<1><<<dim3(256,4), 256, 0, stream>>>(W_ws, proj_wt, proj_b, 1.0f, (void*)d_out);
}